// Round 13
// baseline (196.447 us; speedup 1.0000x reference)
//
#include <hip/hip_runtime.h>
#include <hip/hip_fp16.h>

#define N_CLASS_C 6
#define MAX_WORDS 33344          // cell-table words; supports n_atoms <= 100,032
#define FILTER_BLOCK 1024
#define FILTER_GRID 256

typedef int vint4 __attribute__((ext_vector_type(4)));
typedef unsigned vuint4 __attribute__((ext_vector_type(4)));

// 8-byte packed atom record: fp16 x,y,z,radius. One dwordx2 gather per atom.
struct alignas(8) HAtom {
    __half x, y, z, r;
};

// ---------------- ws layout ----------------
// [64..96)  : probe scratch (never read)
// [256..)   : HAtom table
// then      : packed cell words (3 atoms / u32)

__global__ __launch_bounds__(256) void prep(
    const float* __restrict__ coords,
    const float* __restrict__ radii,
    const int* __restrict__ names,
    const float* __restrict__ tol,
    int n_radii,
    HAtom* __restrict__ atoms,
    unsigned* __restrict__ cellsg,
    float* __restrict__ out,
    int n_words, int n_atoms) {
    if (blockIdx.x == 0 && threadIdx.x < N_CLASS_C) out[threadIdx.x] = 0.0f;

    __shared__ float sh[4];
    __shared__ float shw;
    {
        float m = 0.0f;
        for (int i = threadIdx.x; i < n_radii; i += blockDim.x)
            m = fmaxf(m, radii[i]);
#pragma unroll
        for (int off = 32; off > 0; off >>= 1) m = fmaxf(m, __shfl_down(m, off, 64));
        if ((threadIdx.x & 63) == 0) sh[threadIdx.x >> 6] = m;
        __syncthreads();
        if (threadIdx.x == 0) {
            float mm = fmaxf(fmaxf(sh[0], sh[1]), fmaxf(sh[2], sh[3]));
            float tmax = -1e30f;
            for (int c = 0; c < N_CLASS_C; ++c) tmax = fmaxf(tmax, tol[c]);
            shw = fmaxf(2.0f * mm + tmax, 1e-2f) + 1e-3f;
        }
        __syncthreads();
    }
    float inv = 1.0f / shw;

    int t = blockIdx.x * blockDim.x + threadIdx.x;
    if (t < n_words) {
        unsigned word = 0;
#pragma unroll
        for (int s = 0; s < 3; ++s) {
            int i = 3 * t + s;
            unsigned c = 0;
            if (i < n_atoms) {
                float x = coords[3 * i + 0];
                float y = coords[3 * i + 1];
                float z = coords[3 * i + 2];
                HAtom a;
                a.x = __float2half(x);
                a.y = __float2half(y);
                a.z = __float2half(z);
                a.r = __float2half(radii[names[i]]);
                atoms[i] = a;
                int cx = (int)floorf(x * inv) + 4;
                int cy = (int)floorf(y * inv) + 4;
                int cz = (int)floorf(z * inv) + 8;
                cx = min(max(cx, 0), 7);
                cy = min(max(cy, 0), 7);
                cz = min(max(cz, 0), 15);
                c = (unsigned)cx | ((unsigned)cy << 3) | ((unsigned)cz << 6);
            }
            word |= c << (10 * s);
        }
        cellsg[t] = word;
    }
}

__device__ __forceinline__ unsigned cell_lookup(const unsigned* cells, int i) {
    unsigned q = (unsigned)(((unsigned long long)(unsigned)i * 0xAAAAAAABull) >> 33);
    unsigned r = (unsigned)i - 3u * q;
    return (cells[q] >> (10u * r)) & 0x3FFu;
}

__device__ __forceinline__ int cell_near(unsigned ca, unsigned cb) {
    int dx = abs((int)(ca & 7u) - (int)(cb & 7u));
    int dy = abs((int)((ca >> 3) & 7u) - (int)((cb >> 3) & 7u));
    int dz = abs((int)((ca >> 6) & 15u) - (int)((cb >> 6) & 15u));
    return (dx | dy | dz) <= 1;
}

__device__ __forceinline__ float hdist_base(const HAtom& A, const HAtom& B) {
    float dx = __half2float(A.x) - __half2float(B.x);
    float dy = __half2float(A.y) - __half2float(B.y);
    float dz = __half2float(A.z) - __half2float(B.z);
    float dist = sqrtf(dx * dx + dy * dy + dz * dz + 1e-12f);
    return (__half2float(A.r) + __half2float(B.r)) - dist;
}

__device__ __forceinline__ void do_pair(
    int p, int a0, int a1,
    const HAtom* __restrict__ atoms, const int* __restrict__ masks,
    const float* tc, float tmax, float* s, int n_pairs) {
    HAtom A = atoms[a0];
    HAtom B = atoms[a1];
    float base = hdist_base(A, B);
    if (base + tmax > 0.0f) {
#pragma unroll
        for (int c = 0; c < N_CLASS_C; ++c) {
            if (masks[(size_t)c * n_pairs + p])
                s[c] += fmaxf(base + tc[c], 0.0f);
        }
    }
}

// Real filter — byte-identical inner structure to round 12 (the 31.3 us run).
__global__ __launch_bounds__(FILTER_BLOCK) void clash_filtered(
    const int* __restrict__ pairs,
    const HAtom* __restrict__ atoms,
    const unsigned* __restrict__ cellsg,
    const int* __restrict__ masks,
    const float* __restrict__ tol,
    const float* __restrict__ weight,
    float* __restrict__ out,
    int n_pairs, int n_words) {
    __shared__ unsigned cells[MAX_WORDS];
    {
        const vuint4* src4 = reinterpret_cast<const vuint4*>(cellsg);
        int nw4 = n_words >> 2;
        for (int i = threadIdx.x; i < nw4; i += FILTER_BLOCK) {
            vuint4 v = src4[i];
            cells[4 * i + 0] = v.x;
            cells[4 * i + 1] = v.y;
            cells[4 * i + 2] = v.z;
            cells[4 * i + 3] = v.w;
        }
        for (int i = (nw4 << 2) + threadIdx.x; i < n_words; i += FILTER_BLOCK)
            cells[i] = cellsg[i];
    }

    float tc[N_CLASS_C];
#pragma unroll
    for (int c = 0; c < N_CLASS_C; ++c) tc[c] = tol[c];
    float tmax = tc[0];
#pragma unroll
    for (int c = 1; c < N_CLASS_C; ++c) tmax = fmaxf(tmax, tc[c]);

    float s[N_CLASS_C];
#pragma unroll
    for (int c = 0; c < N_CLASS_C; ++c) s[c] = 0.0f;

    __syncthreads();

    const vint4* pairs4 = reinterpret_cast<const vint4*>(pairs);
    const int npair2 = n_pairs >> 1;
    const int stride = gridDim.x * FILTER_BLOCK;
    for (int q = blockIdx.x * FILTER_BLOCK + threadIdx.x; q < npair2; q += stride) {
        vint4 pq = pairs4[q];
        unsigned ca0 = cell_lookup(cells, pq.x);
        unsigned cb0 = cell_lookup(cells, pq.y);
        unsigned ca1 = cell_lookup(cells, pq.z);
        unsigned cb1 = cell_lookup(cells, pq.w);
        int hit0 = cell_near(ca0, cb0);
        int hit1 = cell_near(ca1, cb1);
        if (hit0) do_pair(2 * q, pq.x, pq.y, atoms, masks, tc, tmax, s, n_pairs);
        if (hit1) do_pair(2 * q + 1, pq.z, pq.w, atoms, masks, tc, tmax, s, n_pairs);
    }

    if ((n_pairs & 1) && blockIdx.x == 0 && threadIdx.x == 0) {
        int p = n_pairs - 1;
        do_pair(p, pairs[2 * p], pairs[2 * p + 1], atoms, masks, tc, tmax, s, n_pairs);
    }

    __shared__ float shsum[N_CLASS_C];
    if (threadIdx.x < N_CLASS_C) shsum[threadIdx.x] = 0.0f;
    __syncthreads();
#pragma unroll
    for (int c = 0; c < N_CLASS_C; ++c) {
        float v = s[c];
#pragma unroll
        for (int off = 32; off > 0; off >>= 1) v += __shfl_down(v, off, 64);
        if ((threadIdx.x & 63) == 0 && v != 0.0f) atomicAdd(&shsum[c], v);
    }
    __syncthreads();
    if (threadIdx.x < N_CLASS_C) {
        float expw = expf(weight[0]);
        atomicAdd(&out[threadIdx.x], shsum[threadIdx.x] * expw);
    }
}

// DIAGNOSTIC probe: identical pair-stream loop + identical LDS allocation
// (dummy-touched so occupancy matches: 1 block/CU, 16 waves), but no cell
// fill, no lookups, no survivor work. Writes only to ws scratch.
__global__ __launch_bounds__(FILTER_BLOCK) void stream_probe(
    const int* __restrict__ pairs,
    float* __restrict__ scratch,
    int n_pairs) {
    __shared__ unsigned dummy[MAX_WORDS];
    dummy[threadIdx.x] = threadIdx.x;
    __syncthreads();
    int acc = (int)dummy[threadIdx.x ^ 1];

    const vint4* pairs4 = reinterpret_cast<const vint4*>(pairs);
    const int npair2 = n_pairs >> 1;
    const int stride = gridDim.x * FILTER_BLOCK;
    for (int q = blockIdx.x * FILTER_BLOCK + threadIdx.x; q < npair2; q += stride) {
        vint4 pq = pairs4[q];
        acc += pq.x + pq.y + pq.z + pq.w;
    }

    float v = (float)acc * 1e-30f;
#pragma unroll
    for (int off = 32; off > 0; off >>= 1) v += __shfl_down(v, off, 64);
    if ((threadIdx.x & 63) == 0) atomicAdd(scratch, v);
}

// -------- fallback (tiny ws / oversized atom count): direct gather path --------
__global__ void zero_accum_fb(float* accum) {
    if (threadIdx.x < N_CLASS_C) accum[threadIdx.x] = 0.0f;
}

__device__ __forceinline__ void block_reduce_accum_fb(float* s, float* accum) {
    __shared__ float sh[N_CLASS_C];
    if (threadIdx.x < N_CLASS_C) sh[threadIdx.x] = 0.0f;
    __syncthreads();
#pragma unroll
    for (int c = 0; c < N_CLASS_C; ++c) {
        float v = s[c];
#pragma unroll
        for (int off = 32; off > 0; off >>= 1) v += __shfl_down(v, off, 64);
        if ((threadIdx.x & 63) == 0 && v != 0.0f) atomicAdd(&sh[c], v);
    }
    __syncthreads();
    if (threadIdx.x < N_CLASS_C) {
        float v = sh[threadIdx.x];
        if (v != 0.0f) atomicAdd(&accum[threadIdx.x], v);
    }
}

__global__ __launch_bounds__(256) void clash_fallback(
    const int* __restrict__ pairs,
    const float* __restrict__ coords,
    const float* __restrict__ radii,
    const int* __restrict__ names,
    const int* __restrict__ masks,
    const float* __restrict__ tol,
    float* __restrict__ accum,
    int n_pairs) {
    float tc[N_CLASS_C];
#pragma unroll
    for (int c = 0; c < N_CLASS_C; ++c) tc[c] = tol[c];
    float tmax = tc[0];
#pragma unroll
    for (int c = 1; c < N_CLASS_C; ++c) tmax = fmaxf(tmax, tc[c]);
    float s[N_CLASS_C];
#pragma unroll
    for (int c = 0; c < N_CLASS_C; ++c) s[c] = 0.0f;

    const int tid = blockIdx.x * blockDim.x + threadIdx.x;
    const int stride = gridDim.x * blockDim.x;
    for (int p = tid; p < n_pairs; p += stride) {
        int a0 = pairs[2 * p], a1 = pairs[2 * p + 1];
        float dx = coords[3 * a0] - coords[3 * a1];
        float dy = coords[3 * a0 + 1] - coords[3 * a1 + 1];
        float dz = coords[3 * a0 + 2] - coords[3 * a1 + 2];
        float dist = sqrtf(dx * dx + dy * dy + dz * dz + 1e-12f);
        float base = (radii[names[a0]] + radii[names[a1]]) - dist;
        if (base + tmax > 0.0f) {
#pragma unroll
            for (int c = 0; c < N_CLASS_C; ++c) {
                if (masks[(size_t)c * n_pairs + p])
                    s[c] += fmaxf(base + tc[c], 0.0f);
            }
        }
    }
    block_reduce_accum_fb(s, accum);
}

__global__ void finalize_fb(const float* __restrict__ accum,
                            const float* __restrict__ w,
                            float* __restrict__ out) {
    int c = threadIdx.x;
    if (c < N_CLASS_C) {
        float scale = expf(w[0]);
        out[c] = accum[c] * scale;
    }
}

extern "C" void kernel_launch(void* const* d_in, const int* in_sizes, int n_in,
                              void* d_out, int out_size, void* d_ws, size_t ws_size,
                              hipStream_t stream) {
    const float* coords = (const float*)d_in[0];
    const float* radii  = (const float*)d_in[1];
    const float* tol    = (const float*)d_in[2];
    const float* weight = (const float*)d_in[3];
    const int* names    = (const int*)d_in[4];
    const int* pairs    = (const int*)d_in[5];
    const int* masks    = (const int*)d_in[6];
    float* out = (float*)d_out;

    int n_atoms = in_sizes[4];
    int n_radii = in_sizes[1];
    int n_pairs = in_sizes[5] / 2;

    int n_words = (n_atoms + 2) / 3;
    size_t atoms_off = 256;
    size_t atoms_bytes = (size_t)n_atoms * sizeof(HAtom);
    size_t cells_off = (atoms_off + atoms_bytes + 255) & ~(size_t)255;
    size_t need = cells_off + (size_t)n_words * 4 + 64;

    if (ws_size >= need && n_words <= MAX_WORDS) {
        HAtom* atoms = (HAtom*)((char*)d_ws + atoms_off);
        unsigned* cellsg = (unsigned*)((char*)d_ws + cells_off);
        float* scratch = (float*)((char*)d_ws + 64);   // diagnostic sink

        prep<<<(n_words + 255) / 256, 256, 0, stream>>>(
            coords, radii, names, tol, n_radii, atoms, cellsg, out,
            n_words, n_atoms);
        clash_filtered<<<FILTER_GRID, FILTER_BLOCK, 0, stream>>>(
            pairs, atoms, cellsg, masks, tol, weight, out, n_pairs, n_words);
        // Diagnostic: 3x stream-only probe (same loads, same LDS footprint).
        stream_probe<<<FILTER_GRID, FILTER_BLOCK, 0, stream>>>(pairs, scratch, n_pairs);
        stream_probe<<<FILTER_GRID, FILTER_BLOCK, 0, stream>>>(pairs, scratch, n_pairs);
        stream_probe<<<FILTER_GRID, FILTER_BLOCK, 0, stream>>>(pairs, scratch, n_pairs);
    } else {
        float* accum = out;
        zero_accum_fb<<<1, 64, 0, stream>>>(accum);
        clash_fallback<<<2048, 256, 0, stream>>>(pairs, coords, radii, names,
                                                 masks, tol, accum, n_pairs);
        finalize_fb<<<1, 64, 0, stream>>>(accum, weight, out);
    }
}

// Round 14
// 33.772 us; speedup vs baseline: 5.8169x; 5.8169x over previous
//
#include <hip/hip_runtime.h>
#include <hip/hip_fp16.h>

#define N_CLASS_C 6
#define MAX_WORDS 33344          // cell-table words; supports n_atoms <= 100,032
#define FILTER_BLOCK 1024
#define FILTER_GRID 256
#define PART_STRIDE 16           // floats per block slot (64 B, own cache line)

typedef int vint4 __attribute__((ext_vector_type(4)));
typedef unsigned vuint4 __attribute__((ext_vector_type(4)));

// 8-byte packed atom record: fp16 x,y,z,radius. One dwordx2 gather per atom.
struct alignas(8) HAtom {
    __half x, y, z, r;
};

// ---------------- ws layout ----------------
// [256 .. 256+16K)  : per-block partials, PART_STRIDE floats each
// [part_end ..)     : HAtom table (256-aligned)
// then              : packed cell words (3 atoms / u32)

__global__ __launch_bounds__(256) void prep(
    const float* __restrict__ coords,
    const float* __restrict__ radii,
    const int* __restrict__ names,
    const float* __restrict__ tol,
    int n_radii,
    HAtom* __restrict__ atoms,
    unsigned* __restrict__ cellsg,
    int n_words, int n_atoms) {
    __shared__ float sh[4];
    __shared__ float shw;
    {
        float m = 0.0f;
        for (int i = threadIdx.x; i < n_radii; i += blockDim.x)
            m = fmaxf(m, radii[i]);
#pragma unroll
        for (int off = 32; off > 0; off >>= 1) m = fmaxf(m, __shfl_down(m, off, 64));
        if ((threadIdx.x & 63) == 0) sh[threadIdx.x >> 6] = m;
        __syncthreads();
        if (threadIdx.x == 0) {
            float mm = fmaxf(fmaxf(sh[0], sh[1]), fmaxf(sh[2], sh[3]));
            float tmax = -1e30f;
            for (int c = 0; c < N_CLASS_C; ++c) tmax = fmaxf(tmax, tol[c]);
            // any clash has dist < 2*rmax + tmax; margin for strictness
            shw = fmaxf(2.0f * mm + tmax, 1e-2f) + 1e-3f;
        }
        __syncthreads();
    }
    float inv = 1.0f / shw;

    int t = blockIdx.x * blockDim.x + threadIdx.x;
    if (t < n_words) {
        unsigned word = 0;
#pragma unroll
        for (int s = 0; s < 3; ++s) {
            int i = 3 * t + s;
            unsigned c = 0;
            if (i < n_atoms) {
                float x = coords[3 * i + 0];
                float y = coords[3 * i + 1];
                float z = coords[3 * i + 2];
                HAtom a;
                a.x = __float2half(x);
                a.y = __float2half(y);
                a.z = __float2half(z);
                a.r = __float2half(radii[names[i]]);
                atoms[i] = a;
                int cx = (int)floorf(x * inv) + 4;
                int cy = (int)floorf(y * inv) + 4;
                int cz = (int)floorf(z * inv) + 8;
                cx = min(max(cx, 0), 7);
                cy = min(max(cy, 0), 7);
                cz = min(max(cz, 0), 15);
                c = (unsigned)cx | ((unsigned)cy << 3) | ((unsigned)cz << 6);
            }
            word |= c << (10 * s);
        }
        cellsg[t] = word;
    }
}

__device__ __forceinline__ unsigned cell_lookup(const unsigned* cells, int i) {
    unsigned q = (unsigned)(((unsigned long long)(unsigned)i * 0xAAAAAAABull) >> 33);
    unsigned r = (unsigned)i - 3u * q;
    return (cells[q] >> (10u * r)) & 0x3FFu;
}

__device__ __forceinline__ int cell_near(unsigned ca, unsigned cb) {
    int dx = abs((int)(ca & 7u) - (int)(cb & 7u));
    int dy = abs((int)((ca >> 3) & 7u) - (int)((cb >> 3) & 7u));
    int dz = abs((int)((ca >> 6) & 15u) - (int)((cb >> 6) & 15u));
    return (dx | dy | dz) <= 1;
}

__device__ __forceinline__ float hdist_base(const HAtom& A, const HAtom& B) {
    float dx = __half2float(A.x) - __half2float(B.x);
    float dy = __half2float(A.y) - __half2float(B.y);
    float dz = __half2float(A.z) - __half2float(B.z);
    float dist = sqrtf(dx * dx + dy * dy + dz * dz + 1e-12f);
    return (__half2float(A.r) + __half2float(B.r)) - dist;
}

__device__ __forceinline__ void do_pair(
    int p, int a0, int a1,
    const HAtom* __restrict__ atoms, const int* __restrict__ masks,
    const float* tc, float tmax, float* s, int n_pairs) {
    HAtom A = atoms[a0];
    HAtom B = atoms[a1];
    float base = hdist_base(A, B);
    if (base + tmax > 0.0f) {
#pragma unroll
        for (int c = 0; c < N_CLASS_C; ++c) {
            if (masks[(size_t)c * n_pairs + p])
                s[c] += fmaxf(base + tc[c], 0.0f);
        }
    }
}

// Main kernel. NO global atomics / fences anywhere (rounds 3, 8-9, 13 all
// implicate same-line global-atomic epilogues in multi-x slowdowns).
// Each block writes its 6 partials to a private padded ws slot.
__global__ __launch_bounds__(FILTER_BLOCK) void clash_filtered(
    const int* __restrict__ pairs,
    const HAtom* __restrict__ atoms,
    const unsigned* __restrict__ cellsg,
    const int* __restrict__ masks,
    const float* __restrict__ tol,
    float* __restrict__ partials,         // FILTER_GRID * PART_STRIDE floats
    int n_pairs, int n_words) {
    __shared__ unsigned cells[MAX_WORDS];
    {
        const vuint4* src4 = reinterpret_cast<const vuint4*>(cellsg);
        int nw4 = n_words >> 2;
        for (int i = threadIdx.x; i < nw4; i += FILTER_BLOCK) {
            vuint4 v = src4[i];
            cells[4 * i + 0] = v.x;
            cells[4 * i + 1] = v.y;
            cells[4 * i + 2] = v.z;
            cells[4 * i + 3] = v.w;
        }
        for (int i = (nw4 << 2) + threadIdx.x; i < n_words; i += FILTER_BLOCK)
            cells[i] = cellsg[i];
    }

    float tc[N_CLASS_C];
#pragma unroll
    for (int c = 0; c < N_CLASS_C; ++c) tc[c] = tol[c];
    float tmax = tc[0];
#pragma unroll
    for (int c = 1; c < N_CLASS_C; ++c) tmax = fmaxf(tmax, tc[c]);

    float s[N_CLASS_C];
#pragma unroll
    for (int c = 0; c < N_CLASS_C; ++c) s[c] = 0.0f;

    __syncthreads();

    const vint4* pairs4 = reinterpret_cast<const vint4*>(pairs);  // 2 pairs/elt
    const int npair2 = n_pairs >> 1;
    const int stride = gridDim.x * FILTER_BLOCK;

    // 2x-unrolled stream loop: two stride-separated int4 loads in flight
    // (4 pairs/thread/iter) before any dependent work.
    int q = blockIdx.x * FILTER_BLOCK + threadIdx.x;
    for (; q + stride < npair2; q += 2 * stride) {
        vint4 pqA = pairs4[q];
        vint4 pqB = pairs4[q + stride];
        unsigned caA0 = cell_lookup(cells, pqA.x);
        unsigned cbA0 = cell_lookup(cells, pqA.y);
        unsigned caA1 = cell_lookup(cells, pqA.z);
        unsigned cbA1 = cell_lookup(cells, pqA.w);
        unsigned caB0 = cell_lookup(cells, pqB.x);
        unsigned cbB0 = cell_lookup(cells, pqB.y);
        unsigned caB1 = cell_lookup(cells, pqB.z);
        unsigned cbB1 = cell_lookup(cells, pqB.w);
        if (cell_near(caA0, cbA0))
            do_pair(2 * q, pqA.x, pqA.y, atoms, masks, tc, tmax, s, n_pairs);
        if (cell_near(caA1, cbA1))
            do_pair(2 * q + 1, pqA.z, pqA.w, atoms, masks, tc, tmax, s, n_pairs);
        int qB = q + stride;
        if (cell_near(caB0, cbB0))
            do_pair(2 * qB, pqB.x, pqB.y, atoms, masks, tc, tmax, s, n_pairs);
        if (cell_near(caB1, cbB1))
            do_pair(2 * qB + 1, pqB.z, pqB.w, atoms, masks, tc, tmax, s, n_pairs);
    }
    if (q < npair2) {
        vint4 pq = pairs4[q];
        unsigned ca0 = cell_lookup(cells, pq.x);
        unsigned cb0 = cell_lookup(cells, pq.y);
        unsigned ca1 = cell_lookup(cells, pq.z);
        unsigned cb1 = cell_lookup(cells, pq.w);
        if (cell_near(ca0, cb0))
            do_pair(2 * q, pq.x, pq.y, atoms, masks, tc, tmax, s, n_pairs);
        if (cell_near(ca1, cb1))
            do_pair(2 * q + 1, pq.z, pq.w, atoms, masks, tc, tmax, s, n_pairs);
    }

    // Odd tail pair: exact path, one thread.
    if ((n_pairs & 1) && blockIdx.x == 0 && threadIdx.x == 0) {
        int p = n_pairs - 1;
        do_pair(p, pairs[2 * p], pairs[2 * p + 1], atoms, masks, tc, tmax, s, n_pairs);
    }

    // Block reduce (LDS atomics only), then plain store to the block's slot.
    __shared__ float shsum[N_CLASS_C];
    if (threadIdx.x < N_CLASS_C) shsum[threadIdx.x] = 0.0f;
    __syncthreads();
#pragma unroll
    for (int c = 0; c < N_CLASS_C; ++c) {
        float v = s[c];
#pragma unroll
        for (int off = 32; off > 0; off >>= 1) v += __shfl_down(v, off, 64);
        if ((threadIdx.x & 63) == 0 && v != 0.0f) atomicAdd(&shsum[c], v);
    }
    __syncthreads();
    if (threadIdx.x < N_CLASS_C)
        partials[blockIdx.x * PART_STRIDE + threadIdx.x] = shsum[threadIdx.x];
}

// Sums per-block partials, scales by exp(weight), writes d_out.
__global__ __launch_bounds__(256) void finalize(
    const float* __restrict__ partials,
    const float* __restrict__ w,
    float* __restrict__ out,
    int nblocks) {
    float s[N_CLASS_C];
#pragma unroll
    for (int c = 0; c < N_CLASS_C; ++c) s[c] = 0.0f;
    for (int i = threadIdx.x; i < nblocks; i += 256) {
#pragma unroll
        for (int c = 0; c < N_CLASS_C; ++c)
            s[c] += partials[i * PART_STRIDE + c];
    }
    __shared__ float sh[N_CLASS_C];
    if (threadIdx.x < N_CLASS_C) sh[threadIdx.x] = 0.0f;
    __syncthreads();
#pragma unroll
    for (int c = 0; c < N_CLASS_C; ++c) {
        float v = s[c];
#pragma unroll
        for (int off = 32; off > 0; off >>= 1) v += __shfl_down(v, off, 64);
        if ((threadIdx.x & 63) == 0 && v != 0.0f) atomicAdd(&sh[c], v);
    }
    __syncthreads();
    if (threadIdx.x < N_CLASS_C)
        out[threadIdx.x] = sh[threadIdx.x] * expf(w[0]);
}

// -------- fallback (tiny ws / oversized atom count): direct gather path --------
__global__ void zero_accum_fb(float* accum) {
    if (threadIdx.x < N_CLASS_C) accum[threadIdx.x] = 0.0f;
}

__device__ __forceinline__ void block_reduce_accum_fb(float* s, float* accum) {
    __shared__ float sh[N_CLASS_C];
    if (threadIdx.x < N_CLASS_C) sh[threadIdx.x] = 0.0f;
    __syncthreads();
#pragma unroll
    for (int c = 0; c < N_CLASS_C; ++c) {
        float v = s[c];
#pragma unroll
        for (int off = 32; off > 0; off >>= 1) v += __shfl_down(v, off, 64);
        if ((threadIdx.x & 63) == 0 && v != 0.0f) atomicAdd(&sh[c], v);
    }
    __syncthreads();
    if (threadIdx.x < N_CLASS_C) {
        float v = sh[threadIdx.x];
        if (v != 0.0f) atomicAdd(&accum[threadIdx.x], v);
    }
}

__global__ __launch_bounds__(256) void clash_fallback(
    const int* __restrict__ pairs,
    const float* __restrict__ coords,
    const float* __restrict__ radii,
    const int* __restrict__ names,
    const int* __restrict__ masks,
    const float* __restrict__ tol,
    float* __restrict__ accum,
    int n_pairs) {
    float tc[N_CLASS_C];
#pragma unroll
    for (int c = 0; c < N_CLASS_C; ++c) tc[c] = tol[c];
    float tmax = tc[0];
#pragma unroll
    for (int c = 1; c < N_CLASS_C; ++c) tmax = fmaxf(tmax, tc[c]);
    float s[N_CLASS_C];
#pragma unroll
    for (int c = 0; c < N_CLASS_C; ++c) s[c] = 0.0f;

    const int tid = blockIdx.x * blockDim.x + threadIdx.x;
    const int stride = gridDim.x * blockDim.x;
    for (int p = tid; p < n_pairs; p += stride) {
        int a0 = pairs[2 * p], a1 = pairs[2 * p + 1];
        float dx = coords[3 * a0] - coords[3 * a1];
        float dy = coords[3 * a0 + 1] - coords[3 * a1 + 1];
        float dz = coords[3 * a0 + 2] - coords[3 * a1 + 2];
        float dist = sqrtf(dx * dx + dy * dy + dz * dz + 1e-12f);
        float base = (radii[names[a0]] + radii[names[a1]]) - dist;
        if (base + tmax > 0.0f) {
#pragma unroll
            for (int c = 0; c < N_CLASS_C; ++c) {
                if (masks[(size_t)c * n_pairs + p])
                    s[c] += fmaxf(base + tc[c], 0.0f);
            }
        }
    }
    block_reduce_accum_fb(s, accum);
}

__global__ void finalize_fb(const float* __restrict__ accum,
                            const float* __restrict__ w,
                            float* __restrict__ out) {
    int c = threadIdx.x;
    if (c < N_CLASS_C) {
        float scale = expf(w[0]);
        out[c] = accum[c] * scale;
    }
}

extern "C" void kernel_launch(void* const* d_in, const int* in_sizes, int n_in,
                              void* d_out, int out_size, void* d_ws, size_t ws_size,
                              hipStream_t stream) {
    const float* coords = (const float*)d_in[0];
    const float* radii  = (const float*)d_in[1];
    const float* tol    = (const float*)d_in[2];
    const float* weight = (const float*)d_in[3];
    const int* names    = (const int*)d_in[4];
    const int* pairs    = (const int*)d_in[5];
    const int* masks    = (const int*)d_in[6];
    float* out = (float*)d_out;

    int n_atoms = in_sizes[4];
    int n_radii = in_sizes[1];
    int n_pairs = in_sizes[5] / 2;

    int n_words = (n_atoms + 2) / 3;
    size_t part_off = 256;
    size_t part_bytes = (size_t)FILTER_GRID * PART_STRIDE * sizeof(float);  // 16 KB
    size_t atoms_off = (part_off + part_bytes + 255) & ~(size_t)255;
    size_t atoms_bytes = (size_t)n_atoms * sizeof(HAtom);
    size_t cells_off = (atoms_off + atoms_bytes + 255) & ~(size_t)255;
    size_t need = cells_off + (size_t)n_words * 4 + 64;

    if (ws_size >= need && n_words <= MAX_WORDS) {
        float* partials = (float*)((char*)d_ws + part_off);
        HAtom* atoms = (HAtom*)((char*)d_ws + atoms_off);
        unsigned* cellsg = (unsigned*)((char*)d_ws + cells_off);

        prep<<<(n_words + 255) / 256, 256, 0, stream>>>(
            coords, radii, names, tol, n_radii, atoms, cellsg,
            n_words, n_atoms);
        clash_filtered<<<FILTER_GRID, FILTER_BLOCK, 0, stream>>>(
            pairs, atoms, cellsg, masks, tol, partials, n_pairs, n_words);
        finalize<<<1, 256, 0, stream>>>(partials, weight, out, FILTER_GRID);
    } else {
        float* accum = out;
        zero_accum_fb<<<1, 64, 0, stream>>>(accum);
        clash_fallback<<<2048, 256, 0, stream>>>(pairs, coords, radii, names,
                                                 masks, tol, accum, n_pairs);
        finalize_fb<<<1, 64, 0, stream>>>(accum, weight, out);
    }
}

// Round 15
// 31.468 us; speedup vs baseline: 6.2427x; 1.0732x over previous
//
#include <hip/hip_runtime.h>
#include <hip/hip_fp16.h>

#define N_CLASS_C 6
#define MAX_WORDS 33344          // cell-table words; supports n_atoms <= 100,032
#define FILTER_BLOCK 1024
#define FILTER_GRID 256

typedef int vint4 __attribute__((ext_vector_type(4)));
typedef unsigned vuint4 __attribute__((ext_vector_type(4)));

// 8-byte packed atom record: fp16 x,y,z,radius. One dwordx2 gather per atom.
struct alignas(8) HAtom {
    __half x, y, z, r;
};

// ---------------- ws layout ----------------
// [256..)   : HAtom table
// then      : packed cell words (3 atoms / u32)

// Fused prep: per-block redundant w-reduce (radii max + tol max), then per
// word t: write 3 HAtom records + the packed cell word. Block 0 zeros d_out
// (filter blocks accumulate into d_out directly; stream order guarantees
// prep completes first — no fence needed).
// cell id: cx(3b) | cy(3b)<<3 | cz(4b)<<6, cell width w, clamped ranges
// x,y: [-4w,4w), z: [-8w,8w). Clamping only adds false positives (extra
// exact checks downstream), never false negatives.
__global__ __launch_bounds__(256) void prep(
    const float* __restrict__ coords,
    const float* __restrict__ radii,
    const int* __restrict__ names,
    const float* __restrict__ tol,
    int n_radii,
    HAtom* __restrict__ atoms,
    unsigned* __restrict__ cellsg,
    float* __restrict__ out,
    int n_words, int n_atoms) {
    if (blockIdx.x == 0 && threadIdx.x < N_CLASS_C) out[threadIdx.x] = 0.0f;

    __shared__ float sh[4];
    __shared__ float shw;
    {
        float m = 0.0f;
        for (int i = threadIdx.x; i < n_radii; i += blockDim.x)
            m = fmaxf(m, radii[i]);
#pragma unroll
        for (int off = 32; off > 0; off >>= 1) m = fmaxf(m, __shfl_down(m, off, 64));
        if ((threadIdx.x & 63) == 0) sh[threadIdx.x >> 6] = m;
        __syncthreads();
        if (threadIdx.x == 0) {
            float mm = fmaxf(fmaxf(sh[0], sh[1]), fmaxf(sh[2], sh[3]));
            float tmax = -1e30f;
            for (int c = 0; c < N_CLASS_C; ++c) tmax = fmaxf(tmax, tol[c]);
            // any clash has dist < 2*rmax + tmax; margin for strictness
            shw = fmaxf(2.0f * mm + tmax, 1e-2f) + 1e-3f;
        }
        __syncthreads();
    }
    float inv = 1.0f / shw;

    int t = blockIdx.x * blockDim.x + threadIdx.x;
    if (t < n_words) {
        unsigned word = 0;
#pragma unroll
        for (int s = 0; s < 3; ++s) {
            int i = 3 * t + s;
            unsigned c = 0;
            if (i < n_atoms) {
                float x = coords[3 * i + 0];
                float y = coords[3 * i + 1];
                float z = coords[3 * i + 2];
                HAtom a;
                a.x = __float2half(x);
                a.y = __float2half(y);
                a.z = __float2half(z);
                a.r = __float2half(radii[names[i]]);
                atoms[i] = a;
                int cx = (int)floorf(x * inv) + 4;
                int cy = (int)floorf(y * inv) + 4;
                int cz = (int)floorf(z * inv) + 8;
                cx = min(max(cx, 0), 7);
                cy = min(max(cy, 0), 7);
                cz = min(max(cz, 0), 15);
                c = (unsigned)cx | ((unsigned)cy << 3) | ((unsigned)cz << 6);
            }
            word |= c << (10 * s);
        }
        cellsg[t] = word;
    }
}

__device__ __forceinline__ unsigned cell_lookup(const unsigned* cells, int i) {
    // q = i / 3 (u32-safe magic), r = i % 3
    unsigned q = (unsigned)(((unsigned long long)(unsigned)i * 0xAAAAAAABull) >> 33);
    unsigned r = (unsigned)i - 3u * q;
    return (cells[q] >> (10u * r)) & 0x3FFu;
}

// Chebyshev cell distance test: true if all axis deltas <= 1.
__device__ __forceinline__ int cell_near(unsigned ca, unsigned cb) {
    int dx = abs((int)(ca & 7u) - (int)(cb & 7u));
    int dy = abs((int)((ca >> 3) & 7u) - (int)((cb >> 3) & 7u));
    int dz = abs((int)((ca >> 6) & 15u) - (int)((cb >> 6) & 15u));
    return (dx | dy | dz) <= 1;
}

__device__ __forceinline__ float hdist_base(const HAtom& A, const HAtom& B) {
    float dx = __half2float(A.x) - __half2float(B.x);
    float dy = __half2float(A.y) - __half2float(B.y);
    float dz = __half2float(A.z) - __half2float(B.z);
    float dist = sqrtf(dx * dx + dy * dy + dz * dz + 1e-12f);
    return (__half2float(A.r) + __half2float(B.r)) - dist;
}

// Exact per-pair path for filter survivors (and the odd tail).
__device__ __forceinline__ void do_pair(
    int p, int a0, int a1,
    const HAtom* __restrict__ atoms, const int* __restrict__ masks,
    const float* tc, float tmax, float* s, int n_pairs) {
    HAtom A = atoms[a0];
    HAtom B = atoms[a1];
    float base = hdist_base(A, B);
    if (base + tmax > 0.0f) {
#pragma unroll
        for (int c = 0; c < N_CLASS_C; ++c) {
            if (masks[(size_t)c * n_pairs + p])
                s[c] += fmaxf(base + tc[c], 0.0f);
        }
    }
}

// Main kernel: LDS-resident cell table filters pairs without any VMEM
// request; only the surviving pairs issue the 2 scattered atom gathers.
// Processes 2 pairs per iteration (int4 load) for ILP/MLP.
// Epilogue: block partials are scaled by exp(weight) and atomically added
// straight into d_out (prep zeroed it; stream order = sync). Measured best:
// r12 = 31.3 us. Do NOT add fences/tickets (3x slowdown, r8-9), deeper
// unrolls or a separate finalize node (+2.5 us, r14).
__global__ __launch_bounds__(FILTER_BLOCK) void clash_filtered(
    const int* __restrict__ pairs,        // 2 * n_pairs
    const HAtom* __restrict__ atoms,
    const unsigned* __restrict__ cellsg,  // n_words packed cells
    const int* __restrict__ masks,        // N_CLASS * n_pairs
    const float* __restrict__ tol,
    const float* __restrict__ weight,
    float* __restrict__ out,
    int n_pairs, int n_words) {
    __shared__ unsigned cells[MAX_WORDS];
    {
        const vuint4* src4 = reinterpret_cast<const vuint4*>(cellsg);
        int nw4 = n_words >> 2;
        for (int i = threadIdx.x; i < nw4; i += FILTER_BLOCK) {
            vuint4 v = src4[i];
            cells[4 * i + 0] = v.x;
            cells[4 * i + 1] = v.y;
            cells[4 * i + 2] = v.z;
            cells[4 * i + 3] = v.w;
        }
        for (int i = (nw4 << 2) + threadIdx.x; i < n_words; i += FILTER_BLOCK)
            cells[i] = cellsg[i];
    }

    float tc[N_CLASS_C];
#pragma unroll
    for (int c = 0; c < N_CLASS_C; ++c) tc[c] = tol[c];
    float tmax = tc[0];
#pragma unroll
    for (int c = 1; c < N_CLASS_C; ++c) tmax = fmaxf(tmax, tc[c]);

    float s[N_CLASS_C];
#pragma unroll
    for (int c = 0; c < N_CLASS_C; ++c) s[c] = 0.0f;

    __syncthreads();

    const vint4* pairs4 = reinterpret_cast<const vint4*>(pairs);  // 2 pairs/elt
    const int npair2 = n_pairs >> 1;
    const int stride = gridDim.x * FILTER_BLOCK;
    for (int q = blockIdx.x * FILTER_BLOCK + threadIdx.x; q < npair2; q += stride) {
        vint4 pq = pairs4[q];
        unsigned ca0 = cell_lookup(cells, pq.x);
        unsigned cb0 = cell_lookup(cells, pq.y);
        unsigned ca1 = cell_lookup(cells, pq.z);
        unsigned cb1 = cell_lookup(cells, pq.w);
        int hit0 = cell_near(ca0, cb0);
        int hit1 = cell_near(ca1, cb1);
        if (hit0) do_pair(2 * q, pq.x, pq.y, atoms, masks, tc, tmax, s, n_pairs);
        if (hit1) do_pair(2 * q + 1, pq.z, pq.w, atoms, masks, tc, tmax, s, n_pairs);
    }

    // Odd tail pair: exact path, one thread.
    if ((n_pairs & 1) && blockIdx.x == 0 && threadIdx.x == 0) {
        int p = n_pairs - 1;
        do_pair(p, pairs[2 * p], pairs[2 * p + 1], atoms, masks, tc, tmax, s, n_pairs);
    }

    // Block reduce, then scale by exp(weight) and add into d_out.
    __shared__ float shsum[N_CLASS_C];
    if (threadIdx.x < N_CLASS_C) shsum[threadIdx.x] = 0.0f;
    __syncthreads();
#pragma unroll
    for (int c = 0; c < N_CLASS_C; ++c) {
        float v = s[c];
#pragma unroll
        for (int off = 32; off > 0; off >>= 1) v += __shfl_down(v, off, 64);
        if ((threadIdx.x & 63) == 0 && v != 0.0f) atomicAdd(&shsum[c], v);
    }
    __syncthreads();
    if (threadIdx.x < N_CLASS_C) {
        float expw = expf(weight[0]);
        atomicAdd(&out[threadIdx.x], shsum[threadIdx.x] * expw);
    }
}

// -------- fallback (tiny ws / oversized atom count): direct gather path --------
__global__ void zero_accum_fb(float* accum) {
    if (threadIdx.x < N_CLASS_C) accum[threadIdx.x] = 0.0f;
}

__device__ __forceinline__ void block_reduce_accum_fb(float* s, float* accum) {
    __shared__ float sh[N_CLASS_C];
    if (threadIdx.x < N_CLASS_C) sh[threadIdx.x] = 0.0f;
    __syncthreads();
#pragma unroll
    for (int c = 0; c < N_CLASS_C; ++c) {
        float v = s[c];
#pragma unroll
        for (int off = 32; off > 0; off >>= 1) v += __shfl_down(v, off, 64);
        if ((threadIdx.x & 63) == 0 && v != 0.0f) atomicAdd(&sh[c], v);
    }
    __syncthreads();
    if (threadIdx.x < N_CLASS_C) {
        float v = sh[threadIdx.x];
        if (v != 0.0f) atomicAdd(&accum[threadIdx.x], v);
    }
}

__global__ __launch_bounds__(256) void clash_fallback(
    const int* __restrict__ pairs,
    const float* __restrict__ coords,
    const float* __restrict__ radii,
    const int* __restrict__ names,
    const int* __restrict__ masks,
    const float* __restrict__ tol,
    float* __restrict__ accum,
    int n_pairs) {
    float tc[N_CLASS_C];
#pragma unroll
    for (int c = 0; c < N_CLASS_C; ++c) tc[c] = tol[c];
    float tmax = tc[0];
#pragma unroll
    for (int c = 1; c < N_CLASS_C; ++c) tmax = fmaxf(tmax, tc[c]);
    float s[N_CLASS_C];
#pragma unroll
    for (int c = 0; c < N_CLASS_C; ++c) s[c] = 0.0f;

    const int tid = blockIdx.x * blockDim.x + threadIdx.x;
    const int stride = gridDim.x * blockDim.x;
    for (int p = tid; p < n_pairs; p += stride) {
        int a0 = pairs[2 * p], a1 = pairs[2 * p + 1];
        float dx = coords[3 * a0] - coords[3 * a1];
        float dy = coords[3 * a0 + 1] - coords[3 * a1 + 1];
        float dz = coords[3 * a0 + 2] - coords[3 * a1 + 2];
        float dist = sqrtf(dx * dx + dy * dy + dz * dz + 1e-12f);
        float base = (radii[names[a0]] + radii[names[a1]]) - dist;
        if (base + tmax > 0.0f) {
#pragma unroll
            for (int c = 0; c < N_CLASS_C; ++c) {
                if (masks[(size_t)c * n_pairs + p])
                    s[c] += fmaxf(base + tc[c], 0.0f);
            }
        }
    }
    block_reduce_accum_fb(s, accum);
}

__global__ void finalize_fb(const float* __restrict__ accum,
                            const float* __restrict__ w,
                            float* __restrict__ out) {
    int c = threadIdx.x;
    if (c < N_CLASS_C) {
        float scale = expf(w[0]);
        out[c] = accum[c] * scale;
    }
}

extern "C" void kernel_launch(void* const* d_in, const int* in_sizes, int n_in,
                              void* d_out, int out_size, void* d_ws, size_t ws_size,
                              hipStream_t stream) {
    const float* coords = (const float*)d_in[0];
    const float* radii  = (const float*)d_in[1];
    const float* tol    = (const float*)d_in[2];
    const float* weight = (const float*)d_in[3];
    const int* names    = (const int*)d_in[4];
    const int* pairs    = (const int*)d_in[5];
    const int* masks    = (const int*)d_in[6];
    float* out = (float*)d_out;

    int n_atoms = in_sizes[4];
    int n_radii = in_sizes[1];
    int n_pairs = in_sizes[5] / 2;

    int n_words = (n_atoms + 2) / 3;
    size_t atoms_off = 256;
    size_t atoms_bytes = (size_t)n_atoms * sizeof(HAtom);
    size_t cells_off = (atoms_off + atoms_bytes + 255) & ~(size_t)255;
    size_t need = cells_off + (size_t)n_words * 4 + 64;

    if (ws_size >= need && n_words <= MAX_WORDS) {
        HAtom* atoms = (HAtom*)((char*)d_ws + atoms_off);
        unsigned* cellsg = (unsigned*)((char*)d_ws + cells_off);

        prep<<<(n_words + 255) / 256, 256, 0, stream>>>(
            coords, radii, names, tol, n_radii, atoms, cellsg, out,
            n_words, n_atoms);
        clash_filtered<<<FILTER_GRID, FILTER_BLOCK, 0, stream>>>(
            pairs, atoms, cellsg, masks, tol, weight, out, n_pairs, n_words);
    } else {
        float* accum = out;
        zero_accum_fb<<<1, 64, 0, stream>>>(accum);
        clash_fallback<<<2048, 256, 0, stream>>>(pairs, coords, radii, names,
                                                 masks, tol, accum, n_pairs);
        finalize_fb<<<1, 64, 0, stream>>>(accum, weight, out);
    }
}